// Round 7
// baseline (331.715 us; speedup 1.0000x reference)
//
#include <hip/hip_runtime.h>

// TemporalDilatedAttention on gfx950 — round 7
// vs R6: (1) double-buffered LDS staging in the shared GEMM core — ONE
// barrier per K-iter, next iter's global_load_lds issued before the MFMA
// phase (hides the ~900cyc load latency that R6 exposed every iteration:
// 1875 cyc/iter measured); (2) PH split-K 16 with f16 partials (1024 blocks
// = 4/CU, partials still 32 MB aliasing histb); XCD keys kept.

#define DD    1024
#define TALL  16384

typedef _Float16 half8  __attribute__((ext_vector_type(8)));
typedef _Float16 half4v __attribute__((ext_vector_type(4)));
typedef float    floatx4 __attribute__((ext_vector_type(4)));
typedef unsigned int u32;

// ---------------- workspace layout (bytes), ~137.4 MB ----------------
static const size_t OFF_WOT  = 0;          // 2 MB  Wo^T f16
static const size_t OFF_WV16 = 2097152;    // 2 MB  Wv f16
static const size_t OFF_WK16 = 4194304;    // 2 MB  Wk f16
static const size_t OFF_WQ16 = 6291456;    // 2 MB  Wq f16
static const size_t OFF_XB   = 8388608;    // 0.5 MB x f16
static const size_t OFF_G    = 8912896;    // 2 MB  G[h][q][f] f16
static const size_t OFF_WVOT = 11010048;   // 8 MB  WVOT[j][h*1024+k] f16
static const size_t OFF_WQKT = 19398656;   // 8 MB  WQKT[h][f][d] f16
static const size_t OFF_BVWO = 27787264;   // 4 KB  bv@Wo f32
static const size_t OFF_BQK  = 27791360;   // 16 KB bqk[h][f] f32
static const size_t OFF_PHR  = 27807744;   // 2 MB  PHred[q][h*1024+k] f16
static const size_t OFF_OPP  = 29904896;   // 8 MB  FO partials (8 x 256x1024 f32)
static const size_t OFF_HB   = 38293504;   // 32 MB histb; PH f16 partials alias after S
static const size_t OFF_PHP  = OFF_HB;     // 64 x 262144 f16 = 32 MB
static const size_t OFF_HT   = 71848960;   // 32 MB hist^T f16 [feat][t]
static const size_t OFF_S    = 105403392;  // 32 MB S/P f16 [h][q][t]

// ---------------- async global->LDS, 16B per lane ----------------
__device__ __forceinline__ void gl_lds16(const void* g, void* l) {
  __builtin_amdgcn_global_load_lds((const __attribute__((address_space(1))) u32*)g,
                                   (__attribute__((address_space(3))) u32*)l, 16, 0, 0);
}

// ---------------- prep ----------------
// [0,1024): Wo->WoT transpose+cvt   [1024,2048): Wv cvt  [2048,3072): Wk cvt
// [3072,4096): Wq cvt  [4096,4352): x cvt
// [4352,8448): hist 64x64 tiles -> histb + histT (single hist read)
__global__ void prep_kernel(const float* __restrict__ Wo, const float* __restrict__ Wv,
                            const float* __restrict__ Wk, const float* __restrict__ Wq,
                            const float* __restrict__ x, const float* __restrict__ hist,
                            _Float16* __restrict__ WoT, _Float16* __restrict__ Wv16,
                            _Float16* __restrict__ Wk16, _Float16* __restrict__ Wq16,
                            _Float16* __restrict__ xb, _Float16* __restrict__ histb,
                            _Float16* __restrict__ histT) {
  int bid = blockIdx.x, tid = threadIdx.x;
  if (bid < 1024) {
    int k0 = (bid & 31) * 32, n0 = (bid >> 5) * 32;
    __shared__ float t32[32][33];
    int tx = tid & 31, ty = tid >> 5;
#pragma unroll
    for (int i = 0; i < 4; i++) {
      int r = ty + i * 8;
      t32[r][tx] = Wo[(size_t)(k0 + r) * DD + n0 + tx];
    }
    __syncthreads();
#pragma unroll
    for (int i = 0; i < 4; i++) {
      int r = ty + i * 8;
      WoT[(size_t)(n0 + r) * DD + k0 + tx] = (_Float16)t32[tx][r];
    }
  } else if (bid < 4352) {
    const float* src; _Float16* dst; size_t i;
    if (bid < 2048)      { src = Wv; dst = Wv16; i = (size_t)(bid - 1024) * 256 + tid; }
    else if (bid < 3072) { src = Wk; dst = Wk16; i = (size_t)(bid - 2048) * 256 + tid; }
    else if (bid < 4096) { src = Wq; dst = Wq16; i = (size_t)(bid - 3072) * 256 + tid; }
    else                 { src = x;  dst = xb;   i = (size_t)(bid - 4096) * 256 + tid; }
    float4 v = ((const float4*)src)[i];
    half4v h = {(_Float16)v.x, (_Float16)v.y, (_Float16)v.z, (_Float16)v.w};
    *(half4v*)(dst + 4 * i) = h;
  } else {
    int tb = bid - 4352;
    int t0 = (tb & 255) * 64, f0 = (tb >> 8) * 64;
    __shared__ _Float16 lt[64][72];
    int r = tid >> 2, c0 = (tid & 3) * 16;
    half8 s0, s1;
#pragma unroll
    for (int i = 0; i < 4; i++) {
      float4 v = *(const float4*)&hist[(size_t)(t0 + r) * 1024 + f0 + c0 + i * 4];
      half4v h = {(_Float16)v.x, (_Float16)v.y, (_Float16)v.z, (_Float16)v.w};
      *(half4v*)&lt[r][c0 + i * 4] = h;
      if (i < 2) { s0[i*4]=h[0]; s0[i*4+1]=h[1]; s0[i*4+2]=h[2]; s0[i*4+3]=h[3]; }
      else { s1[(i-2)*4]=h[0]; s1[(i-2)*4+1]=h[1]; s1[(i-2)*4+2]=h[2]; s1[(i-2)*4+3]=h[3]; }
    }
    *(half8*)&histb[(size_t)(t0 + r) * 1024 + f0 + c0] = s0;
    *(half8*)&histb[(size_t)(t0 + r) * 1024 + f0 + c0 + 8] = s1;
    __syncthreads();
    int fr = tid >> 2, tc0 = (tid & 3) * 16;
    half8 o0, o1;
#pragma unroll
    for (int j = 0; j < 8; j++) { o0[j] = lt[tc0 + j][fr]; o1[j] = lt[tc0 + 8 + j][fr]; }
    *(half8*)&histT[(size_t)(f0 + fr) * TALL + t0 + tc0] = o0;
    *(half8*)&histT[(size_t)(f0 + fr) * TALL + t0 + tc0 + 8] = o1;
  }
}

// ---------------- double-buffered 128x128 GEMM core -----------------------
// LDS: As/Bs each 8192 f16 (two 4096 buffers). ONE barrier per K-iter:
//   sync (drains prev staging) -> issue next staging -> MFMA on current.
// Buffer being staged at iter k was last ds_read at iter k-1 (ordered by the
// barrier). XOR swizzle as before (2-way banks, free).
__device__ __forceinline__ void gemm_core_db(const _Float16* __restrict__ A, size_t lda,
                                             const _Float16* __restrict__ B, size_t ldb,
                                             int kIters, _Float16* As, _Float16* Bs,
                                             int tid, floatx4 acc[4][4]) {
  int lane = tid & 63, w = tid >> 6;
  int l15 = lane & 15, quad = lane >> 4;
  int wm = (w >> 1) * 64, wn = (w & 1) * 64;
  int swz = ((tid & 3) ^ ((tid >> 3) & 3)) * 8;
  int pch = (quad ^ ((l15 >> 1) & 3)) * 8;
  const char* gA0 = (const char*)(A + (size_t)(tid >> 2) * lda + swz);
  const char* gA1 = (const char*)(A + ((size_t)(tid >> 2) + 64) * lda + swz);
  const char* gB0 = (const char*)(B + (size_t)(tid >> 2) * ldb + swz);
  const char* gB1 = (const char*)(B + ((size_t)(tid >> 2) + 64) * ldb + swz);
  int so = w * 512;
  gl_lds16(gA0, As + so); gl_lds16(gA1, As + 2048 + so);
  gl_lds16(gB0, Bs + so); gl_lds16(gB1, Bs + 2048 + so);
  for (int kk = 0; kk < kIters; kk++) {
    int cur = (kk & 1) * 4096;
    __syncthreads();
    if (kk + 1 < kIters) {
      int nxt = 4096 - cur;
      size_t off = (size_t)(kk + 1) * 64;
      gl_lds16(gA0 + off, As + nxt + so); gl_lds16(gA1 + off, As + nxt + 2048 + so);
      gl_lds16(gB0 + off, Bs + nxt + so); gl_lds16(gB1 + off, Bs + nxt + 2048 + so);
    }
    const _Float16* Ac = As + cur;
    const _Float16* Bc = Bs + cur;
    half8 a[4];
#pragma unroll
    for (int mi = 0; mi < 4; mi++) a[mi] = *(const half8*)&Ac[(wm + mi * 16 + l15) * 32 + pch];
#pragma unroll
    for (int ni = 0; ni < 4; ni++) {
      half8 b8 = *(const half8*)&Bc[(wn + ni * 16 + l15) * 32 + pch];
#pragma unroll
      for (int mi = 0; mi < 4; mi++)
        acc[mi][ni] = __builtin_amdgcn_mfma_f32_16x16x32_f16(a[mi], b8, acc[mi][ni], 0, 0, 0);
    }
  }
}

// ---------------- generic single-B GEMM ----------------
template <bool OUTF32>
__launch_bounds__(256, 3)
__global__ void gemm_f16_kernel(const _Float16* __restrict__ A, size_t lda, size_t aoffz,
                                const _Float16* __restrict__ B, size_t ldb, size_t boffz,
                                int kIters, const float* __restrict__ bias, size_t biasoffz,
                                float scale, void* __restrict__ C, size_t ldc, size_t coffz) {
  __shared__ __align__(16) _Float16 As[8192];
  __shared__ __align__(16) _Float16 Bs[8192];
  int tid = threadIdx.x;
  const _Float16* Ab = A + aoffz * blockIdx.z + (size_t)(blockIdx.y * 128) * lda;
  const _Float16* Bb = B + boffz * blockIdx.z + (size_t)(blockIdx.x * 128) * ldb;
  floatx4 acc[4][4];
  floatx4 zero = {0.f, 0.f, 0.f, 0.f};
#pragma unroll
  for (int a = 0; a < 4; a++)
#pragma unroll
    for (int b = 0; b < 4; b++) acc[a][b] = zero;
  gemm_core_db(Ab, lda, Bb, ldb, kIters, As, Bs, tid, acc);
  int lane = tid & 63, w = tid >> 6;
  int l15 = lane & 15, quad = lane >> 4;
  int wm = (w >> 1) * 64, wn = (w & 1) * 64;
#pragma unroll
  for (int mi = 0; mi < 4; mi++)
#pragma unroll
    for (int ni = 0; ni < 4; ni++) {
      int colg = blockIdx.x * 128 + wn + ni * 16 + l15;
      float bv = bias ? bias[biasoffz * blockIdx.z + colg] : 0.f;
#pragma unroll
      for (int r = 0; r < 4; r++) {
        int rowg = blockIdx.y * 128 + wm + mi * 16 + quad * 4 + r;
        float v = (acc[mi][ni][r] + bv) * scale;
        size_t idx = coffz * blockIdx.z + (size_t)rowg * ldc + colg;
        if (OUTF32) ((float*)C)[idx] = v;
        else ((_Float16*)C)[idx] = (_Float16)v;
      }
    }
}

// ---------------- wpack: WVOT + WQKT gemms + bvwo + bqk dots --------------
__launch_bounds__(256, 3)
__global__ void wpack_kernel(const _Float16* __restrict__ WoT, const _Float16* __restrict__ Wv16,
                             const _Float16* __restrict__ Wk16, const _Float16* __restrict__ Wq16,
                             const float* __restrict__ bv, const float* __restrict__ bq,
                             _Float16* __restrict__ WVOT, _Float16* __restrict__ WQKT,
                             float* __restrict__ bvwo, float* __restrict__ bqk) {
  __shared__ __align__(16) _Float16 As[8192];
  __shared__ __align__(16) _Float16 Bs[8192];
  int bid = blockIdx.x, tid = threadIdx.x;
  if (bid < 512) {
    bool isQK = bid >= 256;                 // block-uniform selects, ONE gemm path
    int g = bid & 255;
    int x = g & 7, y = (g >> 3) & 7, z = g >> 6;
    const _Float16* A = isQK ? Wk16 : WoT;
    const _Float16* B = isQK ? Wq16 : Wv16;
    const _Float16* Ab = A + 256 * z + (size_t)(y * 128) * 1024;
    const _Float16* Bb = B + 256 * z + (size_t)(x * 128) * 1024;
    floatx4 acc[4][4];
    floatx4 zero = {0.f, 0.f, 0.f, 0.f};
#pragma unroll
    for (int a = 0; a < 4; a++)
#pragma unroll
      for (int b = 0; b < 4; b++) acc[a][b] = zero;
    gemm_core_db(Ab, 1024, Bb, 1024, 8, As, Bs, tid, acc);
    float scale = isQK ? 0.0625f : 1.0f;
    _Float16* C = isQK ? WQKT : WVOT;
    size_t ldc = isQK ? 1024 : 4096;
    size_t zoff = isQK ? (size_t)1048576 * z : (size_t)1024 * z;
    int lane = tid & 63, w = tid >> 6;
    int l15 = lane & 15, quad = lane >> 4;
    int wm = (w >> 1) * 64, wn = (w & 1) * 64;
#pragma unroll
    for (int mi = 0; mi < 4; mi++)
#pragma unroll
      for (int ni = 0; ni < 4; ni++) {
        int col = x * 128 + wn + ni * 16 + l15;
#pragma unroll
        for (int r = 0; r < 4; r++) {
          int row = y * 128 + wm + mi * 16 + quad * 4 + r;
          C[zoff + (size_t)row * ldc + col] = (_Float16)(acc[mi][ni][r] * scale);
        }
      }
  } else if (bid < 516) {
    int j = (bid - 512) * 256 + tid;
    const half8* row = (const half8*)(WoT + (size_t)j * 1024);
    float a = 0.f;
    for (int c = 0; c < 128; c++) {
      half8 w8 = row[c];
#pragma unroll
      for (int e = 0; e < 8; e++) a += bv[c * 8 + e] * (float)w8[e];
    }
    bvwo[j] = a;
  } else {
    int idx = (bid - 516) * 256 + tid;
    int h = idx >> 10, f = idx & 1023;
    const _Float16* row = Wk16 + (size_t)f * 1024 + h * 256;
    float a = 0.f;
    for (int n = 0; n < 256; n++) a += bq[h * 256 + n] * (float)row[n];
    bqk[idx] = a * 0.0625f;
  }
}

// ---------------- S gemm, XCD-swizzled: bid%8 = x&7 ----------------
__launch_bounds__(256, 3)
__global__ void gemm_s_kernel(const _Float16* __restrict__ G, const _Float16* __restrict__ histb,
                              _Float16* __restrict__ S) {
  __shared__ __align__(16) _Float16 As[8192];
  __shared__ __align__(16) _Float16 Bs[8192];
  int bid = blockIdx.x, tid = threadIdx.x;
  int b7 = bid & 7, rr = bid >> 3;
  int x = ((rr & 15) << 3) | b7;           // 0..127 t-strip
  int yh = rr >> 4;
  int y = yh & 1, h = yh >> 1;
  const _Float16* Ab = G + (size_t)h * 262144 + (size_t)(y * 128) * 1024;
  const _Float16* Bb = histb + (size_t)(x * 128) * 1024;
  floatx4 acc[4][4];
  floatx4 zero = {0.f, 0.f, 0.f, 0.f};
#pragma unroll
  for (int a = 0; a < 4; a++)
#pragma unroll
    for (int b = 0; b < 4; b++) acc[a][b] = zero;
  gemm_core_db(Ab, 1024, Bb, 1024, 32, As, Bs, tid, acc);
  int lane = tid & 63, w = tid >> 6;
  int l15 = lane & 15, quad = lane >> 4;
  int wm = (w >> 1) * 64, wn = (w & 1) * 64;
#pragma unroll
  for (int mi = 0; mi < 4; mi++)
#pragma unroll
    for (int ni = 0; ni < 4; ni++) {
      int col = x * 128 + wn + ni * 16 + l15;
#pragma unroll
      for (int r = 0; r < 4; r++) {
        int row = y * 128 + wm + mi * 16 + quad * 4 + r;
        S[(size_t)h * 4194304 + (size_t)row * TALL + col] = (_Float16)acc[mi][ni][r];
      }
    }
}

// ---------------- softmax (no max phase; exp register-cached) -------------
__global__ void softmax_kernel(_Float16* __restrict__ S, const float* __restrict__ dil_w) {
  int r = blockIdx.x, tid = threadIdx.x;
  _Float16* row = S + (size_t)r * TALL;
  int lane = tid & 63;
  float ef[8][8];
  float es[8];
  __shared__ float Zf[64];
  __shared__ float Zd[4];
  __shared__ float cf[64];
#pragma unroll
  for (int i = 0; i < 8; i++) {
    half8 v = *(const half8*)&row[((size_t)i * 256 + tid) * 8];
    float s = 0.f;
#pragma unroll
    for (int j = 0; j < 8; j++) { float e = __expf((float)v[j]); ef[i][j] = e; s += e; }
#pragma unroll
    for (int off = 1; off <= 16; off <<= 1) s += __shfl_xor(s, off, 64);
    es[i] = s;
  }
  if ((lane & 31) == 0) {
    int half = tid >> 5;
#pragma unroll
    for (int i = 0; i < 8; i++) Zf[i * 8 + half] = es[i];
  }
  __syncthreads();
  if (tid < 4) {
    int step = 1 << (tid + (tid ? 1 : 0));   // 1,4,8,16
    float z = 0.f;
    for (int f = 0; f < 64; f += step) z += Zf[f];
    Zd[tid] = z;
  }
  __syncthreads();
  if (tid < 64) {
    float w0 = dil_w[0], w1 = dil_w[1], w2 = dil_w[2], w3 = dil_w[3];
    float wmx = fmaxf(fmaxf(w0, w1), fmaxf(w2, w3));
    float e0 = __expf(w0 - wmx), e1 = __expf(w1 - wmx), e2 = __expf(w2 - wmx), e3 = __expf(w3 - wmx);
    float wsum = e0 + e1 + e2 + e3;
    float c = (e0 / wsum) / Zd[0];
    if ((tid & 3) == 0) c += (e1 / wsum) / Zd[1];
    if ((tid & 7) == 0) c += (e2 / wsum) / Zd[2];
    if ((tid & 15) == 0) c += (e3 / wsum) / Zd[3];
    cf[tid] = c * 256.0f;   // x256 keeps P normal in f16; /256 folded into FO
  }
  __syncthreads();
#pragma unroll
  for (int i = 0; i < 8; i++) {
    float c = cf[i * 8 + (tid >> 5)];
    half8 o;
#pragma unroll
    for (int j = 0; j < 8; j++) o[j] = (_Float16)(ef[i][j] * c);
    *(half8*)&row[((size_t)i * 256 + tid) * 8] = o;
  }
}

// ---------------- PH gemm, split-K 16, f16 partials, bid%8 = sp&7 ---------
// grid 1024 = 8 splo x 8 x x 8 (y,h) x 2 sphi; K-chunk 1024 -> 32 iters.
__launch_bounds__(256, 3)
__global__ void gemm_ph_kernel(const _Float16* __restrict__ P, const _Float16* __restrict__ histT,
                               _Float16* __restrict__ part) {
  __shared__ __align__(16) _Float16 As[8192];
  __shared__ __align__(16) _Float16 Bs[8192];
  int bid = blockIdx.x, tid = threadIdx.x;
  int splo = bid & 7, x = (bid >> 3) & 7, yh = (bid >> 6) & 7, sphi = bid >> 9;
  int sp = sphi * 8 + splo;
  int y = yh & 1, h = yh >> 1;
  const _Float16* Ab = P + (size_t)h * 4194304 + (size_t)(y * 128) * TALL + sp * 1024;
  const _Float16* Bb = histT + (size_t)(x * 128) * TALL + sp * 1024;
  floatx4 acc[4][4];
  floatx4 zero = {0.f, 0.f, 0.f, 0.f};
#pragma unroll
  for (int a = 0; a < 4; a++)
#pragma unroll
    for (int b = 0; b < 4; b++) acc[a][b] = zero;
  gemm_core_db(Ab, TALL, Bb, TALL, 32, As, Bs, tid, acc);
  int lane = tid & 63, w = tid >> 6;
  int l15 = lane & 15, quad = lane >> 4;
  int wm = (w >> 1) * 64, wn = (w & 1) * 64;
#pragma unroll
  for (int mi = 0; mi < 4; mi++)
#pragma unroll
    for (int ni = 0; ni < 4; ni++) {
      int k = x * 128 + wn + ni * 16 + l15;
#pragma unroll
      for (int r = 0; r < 4; r++) {
        int q = y * 128 + wm + mi * 16 + quad * 4 + r;
        part[(size_t)(h * 16 + sp) * 262144 + (size_t)q * 1024 + k] = (_Float16)acc[mi][ni][r];
      }
    }
}

// ---------------- reduce 16 f16 PH partials -> PHred[q][h*1024+k] f16 -----
__global__ void reduce_ph_kernel(const _Float16* __restrict__ part, _Float16* __restrict__ PHred) {
  size_t e8 = ((size_t)blockIdx.x * 256 + threadIdx.x) * 8;
  int q = (int)(e8 >> 12);
  int hk = (int)(e8 & 4095);
  int h = hk >> 10, k = hk & 1023;
  float s[8] = {0.f, 0.f, 0.f, 0.f, 0.f, 0.f, 0.f, 0.f};
#pragma unroll
  for (int sp = 0; sp < 16; sp++) {
    half8 p = *(const half8*)&part[(size_t)(h * 16 + sp) * 262144 + (size_t)q * 1024 + k];
#pragma unroll
    for (int e = 0; e < 8; e++) s[e] += (float)p[e];
  }
  half8 o;
#pragma unroll
  for (int e = 0; e < 8; e++) o[e] = (_Float16)s[e];
  *(half8*)&PHred[e8] = o;
}

// ---------------- FO 8-way reduce + bo + bv@Wo + residual + layernorm ------
__global__ void ln_kernel(const float* __restrict__ x, const float* __restrict__ part2,
                          const float* __restrict__ bo, const float* __restrict__ bvwo,
                          const float* __restrict__ gamma, const float* __restrict__ beta,
                          float* __restrict__ out) {
  int b = blockIdx.x, t = threadIdx.x;
  __shared__ float red[8];
  float y[4];
  float sum = 0.f, sq = 0.f;
#pragma unroll
  for (int i = 0; i < 4; i++) {
    int j = t + i * 256;
    float v = x[(size_t)b * 1024 + j] + bo[j] + bvwo[j];
#pragma unroll
    for (int z = 0; z < 8; z++) v += part2[(size_t)z * 262144 + (size_t)b * 1024 + j];
    y[i] = v;
    sum += v;
    sq += v * v;
  }
#pragma unroll
  for (int off = 1; off < 64; off <<= 1) {
    sum += __shfl_xor(sum, off, 64);
    sq += __shfl_xor(sq, off, 64);
  }
  int w = t >> 6, lane = t & 63;
  if (lane == 0) { red[w] = sum; red[4 + w] = sq; }
  __syncthreads();
  sum = red[0] + red[1] + red[2] + red[3];
  sq = red[4] + red[5] + red[6] + red[7];
  float mu = sum * (1.f / 1024.f);
  float var = sq * (1.f / 1024.f) - mu * mu;
  float inv = rsqrtf(var + 1e-5f);
#pragma unroll
  for (int i = 0; i < 4; i++) {
    int j = t + i * 256;
    out[(size_t)b * 1024 + j] = (y[i] - mu) * inv * gamma[j] + beta[j];
  }
}

// ---------------- host launch ----------------
extern "C" void kernel_launch(void* const* d_in, const int* in_sizes, int n_in,
                              void* d_out, int out_size, void* d_ws, size_t ws_size,
                              hipStream_t stream) {
  const float* x     = (const float*)d_in[0];
  const float* hist  = (const float*)d_in[1];
  const float* Wq    = (const float*)d_in[2];
  const float* bq    = (const float*)d_in[3];
  const float* Wk    = (const float*)d_in[4];
  // bk (d_in[5]) dropped exactly: softmax shift invariance.
  const float* Wv    = (const float*)d_in[6];
  const float* bv    = (const float*)d_in[7];
  const float* Wo    = (const float*)d_in[8];
  const float* bo    = (const float*)d_in[9];
  const float* dil_w = (const float*)d_in[10];
  const float* gamma = (const float*)d_in[11];
  const float* beta  = (const float*)d_in[12];
  char* ws = (char*)d_ws;

  _Float16* WoT   = (_Float16*)(ws + OFF_WOT);
  _Float16* Wv16  = (_Float16*)(ws + OFF_WV16);
  _Float16* Wk16  = (_Float16*)(ws + OFF_WK16);
  _Float16* Wq16  = (_Float16*)(ws + OFF_WQ16);
  _Float16* xb    = (_Float16*)(ws + OFF_XB);
  _Float16* G     = (_Float16*)(ws + OFF_G);
  _Float16* WVOT  = (_Float16*)(ws + OFF_WVOT);
  _Float16* WQKT  = (_Float16*)(ws + OFF_WQKT);
  float* bvwo     = (float*)(ws + OFF_BVWO);
  float* bqk      = (float*)(ws + OFF_BQK);
  _Float16* PHred = (_Float16*)(ws + OFF_PHR);
  float* oppart   = (float*)(ws + OFF_OPP);
  _Float16* histb = (_Float16*)(ws + OFF_HB);
  _Float16* phpart= (_Float16*)(ws + OFF_PHP);  // aliases histb (dead after S gemm)
  _Float16* histT = (_Float16*)(ws + OFF_HT);
  _Float16* Sb    = (_Float16*)(ws + OFF_S);

  // 1) prep: WoT, Wv/Wk/Wq/x cvt, hist -> histb + histT (single hist read)
  prep_kernel<<<dim3(8448), 256, 0, stream>>>(Wo, Wv, Wk, Wq, x, hist,
                                              WoT, Wv16, Wk16, Wq16, xb, histb, histT);
  // 2) wpack: WVOT + WQKT + bvwo + bqk in one launch
  wpack_kernel<<<dim3(532), 256, 0, stream>>>(WoT, Wv16, Wk16, Wq16, bv, bq,
                                              WVOT, WQKT, bvwo, bqk);
  // 3) G[h] = x @ WQKT_h^T + bqk_h  (scale 1/16 pre-folded)
  gemm_f16_kernel<false><<<dim3(8, 2, 4), 256, 0, stream>>>(
      xb, 1024, 0, WQKT, 1024, 1048576, 32, bqk, 1024, 1.0f, (void*)G, 1024, 262144);
  // 4) S[h] = G_h @ hist^T (XCD-swizzled)
  gemm_s_kernel<<<dim3(1024), 256, 0, stream>>>(G, histb, Sb);
  // 5) softmax: per-dilation Z, merged frame weights, P in place
  softmax_kernel<<<dim3(1024), 256, 0, stream>>>(Sb, dil_w);
  // 6) PH partials = P_h @ hist (split-K 16, f16 partials, XCD key = sp&7)
  gemm_ph_kernel<<<dim3(1024), 256, 0, stream>>>(Sb, histT, phpart);
  // 7) reduce 16 partials -> PHred[q][h*1024+k] f16
  reduce_ph_kernel<<<dim3(512), 256, 0, stream>>>(phpart, PHred);
  // 8) FO partials = PHred @ WVOT^T (split-K 8; scale 1/256)
  gemm_f16_kernel<true><<<dim3(8, 2, 8), 256, 0, stream>>>(
      PHred, 4096, 512, WVOT, 4096, 512, 16, nullptr, 0, 1.0f / 256.0f,
      (void*)oppart, 1024, 262144);
  // 9) 8-way reduce + bo + bv@Wo + residual + layernorm
  ln_kernel<<<dim3(256), 256, 0, stream>>>(x, oppart, bo, bvwo, gamma, beta, (float*)d_out);
}